// Round 4
// baseline (204.712 us; speedup 1.0000x reference)
//
#include <hip/hip_runtime.h>
#include <hip/hip_cooperative_groups.h>

namespace cg = cooperative_groups;

// FDN reverb == 8-tap sparse FIR + 50/50 mix + global max-abs normalize.
// Single cooperative kernel: compute in registers, grid-sync for max, scale, store.
// No LDS staging: tap reuse distance <= 15.3 KB << 4 MB per-XCD L2, and the
// reuse is intra-block, so global float4 tap loads are L2 hits.
#define T_LEN 8388608
#define NBLK  512                 // 2 blocks/CU, all co-resident (VGPR <= 256)
#define CHUNK (T_LEN / NBLK)      // 16384 outputs per block
#define IT    (CHUNK / 1024)      // 16 groups of float4 per thread -> v[64]

#define D0 1425
#define D1 1780
#define D2 1972
#define D3 2097
#define D4 2558
#define D5 2961
#define D6 3508
#define D7 3825

__device__ __forceinline__ float4 ld4u(const float* p) {
    // 4B-aligned (not 16B) vector load; gfx950 global loads handle this.
    float4 v;
    __builtin_memcpy(&v, p, sizeof(float4));
    return v;
}

__global__ __launch_bounds__(256, 2) void fdn_onepass(
    const float* __restrict__ x, const float* __restrict__ g,
    const float* __restrict__ Q, float* __restrict__ out,
    float* __restrict__ wsf) {
    __shared__ float csh[8];
    __shared__ float wmax[4];
    __shared__ float sinv;

    const int tid = threadIdx.x;
    const int blk = blockIdx.x;

    // combined[n] = g[n] * sum_j Q[j,n]
    if (tid < 8) {
        float s = 0.f;
#pragma unroll
        for (int j = 0; j < 8; ++j) s += Q[j * 8 + tid];
        csh[tid] = s * g[tid];
    }
    __syncthreads();

    const float c0 = csh[0], c1 = csh[1], c2 = csh[2], c3 = csh[3];
    const float c4 = csh[4], c5 = csh[5], c6 = csh[6], c7 = csh[7];

    const int base = blk * CHUNK;
    float v[IT * 4];
    float m = 0.f;

#pragma unroll
    for (int i = 0; i < IT; ++i) {
        const int t0 = base + i * 1024 + tid * 4;
        float4 o;
        if (blk == 0 && i < 4) {
            // boundary: t - D may be negative (only first 4096 samples)
#pragma unroll
            for (int k = 0; k < 4; ++k) {
                const int t = t0 + k;
                float wet = 0.f;
                int s;
                s = t - D0; wet = fmaf(c0, s >= 0 ? x[s] : 0.f, wet);
                s = t - D1; wet = fmaf(c1, s >= 0 ? x[s] : 0.f, wet);
                s = t - D2; wet = fmaf(c2, s >= 0 ? x[s] : 0.f, wet);
                s = t - D3; wet = fmaf(c3, s >= 0 ? x[s] : 0.f, wet);
                s = t - D4; wet = fmaf(c4, s >= 0 ? x[s] : 0.f, wet);
                s = t - D5; wet = fmaf(c5, s >= 0 ? x[s] : 0.f, wet);
                s = t - D6; wet = fmaf(c6, s >= 0 ? x[s] : 0.f, wet);
                s = t - D7; wet = fmaf(c7, s >= 0 ? x[s] : 0.f, wet);
                (&o.x)[k] = fmaf(0.5f, wet, 0.5f * x[t]);
            }
        } else {
            const float4 dry = *(const float4*)(x + t0);
            const float4 a0 = ld4u(x + t0 - D0);
            const float4 a1 = ld4u(x + t0 - D1);
            const float4 a2 = ld4u(x + t0 - D2);
            const float4 a3 = ld4u(x + t0 - D3);
            const float4 a4 = ld4u(x + t0 - D4);
            const float4 a5 = ld4u(x + t0 - D5);
            const float4 a6 = ld4u(x + t0 - D6);
            const float4 a7 = ld4u(x + t0 - D7);
#pragma unroll
            for (int k = 0; k < 4; ++k) {
                float wet = 0.f;
                wet = fmaf(c0, (&a0.x)[k], wet);
                wet = fmaf(c1, (&a1.x)[k], wet);
                wet = fmaf(c2, (&a2.x)[k], wet);
                wet = fmaf(c3, (&a3.x)[k], wet);
                wet = fmaf(c4, (&a4.x)[k], wet);
                wet = fmaf(c5, (&a5.x)[k], wet);
                wet = fmaf(c6, (&a6.x)[k], wet);
                wet = fmaf(c7, (&a7.x)[k], wet);
                (&o.x)[k] = fmaf(0.5f, wet, 0.5f * (&dry.x)[k]);
            }
        }
        v[i * 4 + 0] = o.x; v[i * 4 + 1] = o.y;
        v[i * 4 + 2] = o.z; v[i * 4 + 3] = o.w;
        m = fmaxf(m, fmaxf(fmaxf(fabsf(o.x), fabsf(o.y)),
                           fmaxf(fabsf(o.z), fabsf(o.w))));
    }

    // block max -> per-block slot (written unconditionally; no init needed)
#pragma unroll
    for (int off = 32; off > 0; off >>= 1) m = fmaxf(m, __shfl_down(m, off, 64));
    if ((tid & 63) == 0) wmax[tid >> 6] = m;
    __syncthreads();
    if (tid == 0) {
        float bm = fmaxf(fmaxf(wmax[0], wmax[1]), fmaxf(wmax[2], wmax[3]));
        __hip_atomic_store(wsf + blk, bm, __ATOMIC_RELEASE, __HIP_MEMORY_SCOPE_AGENT);
    }

    cg::this_grid().sync();

    // every block reduces the 512 slots (2 KB, L2-resident)
    float a = __hip_atomic_load(wsf + tid,       __ATOMIC_ACQUIRE, __HIP_MEMORY_SCOPE_AGENT);
    float b = __hip_atomic_load(wsf + tid + 256, __ATOMIC_ACQUIRE, __HIP_MEMORY_SCOPE_AGENT);
    float mm = fmaxf(a, b);
#pragma unroll
    for (int off = 32; off > 0; off >>= 1) mm = fmaxf(mm, __shfl_down(mm, off, 64));
    if ((tid & 63) == 0) wmax[tid >> 6] = mm;
    __syncthreads();
    if (tid == 0)
        sinv = 1.0f / fmaxf(fmaxf(wmax[0], wmax[1]), fmaxf(wmax[2], wmax[3]));
    __syncthreads();
    const float inv = sinv;

    // scale registers, write coalesced float4
#pragma unroll
    for (int i = 0; i < IT; ++i) {
        const int j = base + i * 1024 + tid * 4;
        float4 ov = make_float4(v[i * 4 + 0] * inv, v[i * 4 + 1] * inv,
                                v[i * 4 + 2] * inv, v[i * 4 + 3] * inv);
        *(float4*)(out + j) = ov;
    }
}

extern "C" void kernel_launch(void* const* d_in, const int* in_sizes, int n_in,
                              void* d_out, int out_size, void* d_ws, size_t ws_size,
                              hipStream_t stream) {
    const float* x = (const float*)d_in[0];       // input_sig [1, T]
    const float* g = (const float*)d_in[1];       // feedback_gain [8]
    const float* Q = (const float*)d_in[2];       // orthogonal_matrix [8,8]
    float* out = (float*)d_out;
    float* wsf = (float*)d_ws;                    // 512 per-block max slots

    void* args[] = {(void*)&x, (void*)&g, (void*)&Q, (void*)&out, (void*)&wsf};
    hipLaunchCooperativeKernel((const void*)fdn_onepass, dim3(NBLK), dim3(256),
                               args, 0, stream);
}

// Round 5
// 111.973 us; speedup vs baseline: 1.8282x; 1.8282x over previous
//
#include <hip/hip_runtime.h>

// FDN reverb == 8-tap sparse FIR + 50/50 mix + global max-abs normalize.
// Plain stream-ordered two-pass (NO cooperative launch — grid.sync measured
// ~100us of pure overhead in R3/R4):
//   pass A: LDS-staged FIR, block max only -> slots[blk]  (no 32MB store)
//   pass B: reduce slots -> 1/max, recompute FIR, scale, single 32MB write
// LDS reads exploit delay parity: D1,D2,D6 = 0 mod 4 -> ds_read_b128,
// D4 = 2 mod 4 -> 2x ds_read_b64, D0,D3,D5,D7 = 1 mod 4 -> b32+b64+b32.
#define T_LEN 8388608
#define CHUNK 4096               // outputs per block
#define HALO  3840               // >= max delay (3825), multiple of 4
#define LDSF  (HALO + CHUNK)     // 7936 floats = 31744 B
#define NBLK  (T_LEN / CHUNK)    // 2048 blocks

#define D0 1425   // %4 == 1
#define D1 1780   // %4 == 0
#define D2 1972   // %4 == 0
#define D3 2097   // %4 == 1
#define D4 2558   // %4 == 2
#define D5 2961   // %4 == 1
#define D6 3508   // %4 == 0
#define D7 3825   // %4 == 1

__device__ __forceinline__ void load_odd(const float* q, float* v) {
    // q is (3 mod 4)-dword aligned: scalar, aligned float2, scalar
    float  a  = q[0];
    float2 b  = *(const float2*)(q + 1);
    float  c  = q[3];
    v[0] = a; v[1] = b.x; v[2] = b.y; v[3] = c;
}

// Compute 4 outputs at LDS pointer p (16B-aligned), coefficients c[8].
__device__ __forceinline__ float4 quad_fir(const float* __restrict__ p,
                                           const float* __restrict__ c) {
    float4 dry = *(const float4*)(p);
    float4 t1  = *(const float4*)(p - D1);   // b128
    float4 t2  = *(const float4*)(p - D2);   // b128
    float4 t6  = *(const float4*)(p - D6);   // b128
    float2 t4a = *(const float2*)(p - D4);   // b64 (p-D4 is 2 mod 4)
    float2 t4b = *(const float2*)(p - D4 + 2);
    float t0v[4], t3v[4], t5v[4], t7v[4];
    load_odd(p - D0, t0v);
    load_odd(p - D3, t3v);
    load_odd(p - D5, t5v);
    load_odd(p - D7, t7v);
    float t4v[4] = {t4a.x, t4a.y, t4b.x, t4b.y};

    float4 o;
#pragma unroll
    for (int k = 0; k < 4; ++k) {
        float wet = 0.f;
        wet = fmaf(c[0], t0v[k],      wet);
        wet = fmaf(c[1], (&t1.x)[k],  wet);
        wet = fmaf(c[2], (&t2.x)[k],  wet);
        wet = fmaf(c[3], t3v[k],      wet);
        wet = fmaf(c[4], t4v[k],      wet);
        wet = fmaf(c[5], t5v[k],      wet);
        wet = fmaf(c[6], (&t6.x)[k],  wet);
        wet = fmaf(c[7], t7v[k],      wet);
        (&o.x)[k] = fmaf(0.5f, wet, 0.5f * (&dry.x)[k]);
    }
    return o;
}

// Stage [blk*CHUNK - HALO, blk*CHUNK + CHUNK) into LDS; zeros before t=0.
__device__ __forceinline__ void stage(const float* __restrict__ x, float* smem,
                                      int blk, int tid) {
    const long gs = (long)blk * CHUNK - HALO;
    for (int v4 = tid; v4 < LDSF / 4; v4 += 256) {
        long ga = gs + (long)v4 * 4;
        float4 val = make_float4(0.f, 0.f, 0.f, 0.f);
        if (ga >= 0) val = *(const float4*)(x + ga);
        *(float4*)(smem + v4 * 4) = val;
    }
}

__device__ __forceinline__ void load_coeffs(const float* __restrict__ g,
                                            const float* __restrict__ Q,
                                            float* csh, int tid) {
    if (tid < 8) {
        float s = 0.f;
#pragma unroll
        for (int j = 0; j < 8; ++j) s += Q[j * 8 + tid];
        csh[tid] = s * g[tid];
    }
}

// Pass A: FIR + block max -> slots[blk]. No output store.
__global__ __launch_bounds__(256) void fdn_max(
    const float* __restrict__ x, const float* __restrict__ g,
    const float* __restrict__ Q, float* __restrict__ slots) {
    __shared__ __align__(16) float smem[LDSF];
    __shared__ float csh[8];
    __shared__ float wmax[4];

    const int tid = threadIdx.x;
    const int blk = blockIdx.x;

    load_coeffs(g, Q, csh, tid);
    stage(x, smem, blk, tid);
    __syncthreads();

    float c[8];
#pragma unroll
    for (int n = 0; n < 8; ++n) c[n] = csh[n];

    float m = 0.f;
#pragma unroll
    for (int i = 0; i < CHUNK / 1024; ++i) {
        const float* p = smem + HALO + i * 1024 + tid * 4;
        float4 o = quad_fir(p, c);
        m = fmaxf(m, fmaxf(fmaxf(fabsf(o.x), fabsf(o.y)),
                           fmaxf(fabsf(o.z), fabsf(o.w))));
    }

#pragma unroll
    for (int off = 32; off > 0; off >>= 1) m = fmaxf(m, __shfl_down(m, off, 64));
    if ((tid & 63) == 0) wmax[tid >> 6] = m;
    __syncthreads();
    if (tid == 0)
        slots[blk] = fmaxf(fmaxf(wmax[0], wmax[1]), fmaxf(wmax[2], wmax[3]));
}

// Pass B: reduce slots -> inv, recompute FIR, scale, write.
__global__ __launch_bounds__(256) void fdn_write(
    const float* __restrict__ x, const float* __restrict__ g,
    const float* __restrict__ Q, const float* __restrict__ slots,
    float* __restrict__ out) {
    __shared__ __align__(16) float smem[LDSF];
    __shared__ float csh[8];
    __shared__ float wmax[4];

    const int tid = threadIdx.x;
    const int blk = blockIdx.x;

    load_coeffs(g, Q, csh, tid);

    // each thread covers 8 of the 2048 slots (two float4 loads)
    float4 s0 = *(const float4*)(slots + tid * 8);
    float4 s1 = *(const float4*)(slots + tid * 8 + 4);

    stage(x, smem, blk, tid);

    float m = fmaxf(fmaxf(fmaxf(s0.x, s0.y), fmaxf(s0.z, s0.w)),
                    fmaxf(fmaxf(s1.x, s1.y), fmaxf(s1.z, s1.w)));
#pragma unroll
    for (int off = 32; off > 0; off >>= 1) m = fmaxf(m, __shfl_down(m, off, 64));
    if ((tid & 63) == 0) wmax[tid >> 6] = m;
    __syncthreads();   // covers staging + wmax

    const float inv = 1.0f / fmaxf(fmaxf(wmax[0], wmax[1]),
                                   fmaxf(wmax[2], wmax[3]));
    float c[8];
#pragma unroll
    for (int n = 0; n < 8; ++n) c[n] = csh[n];

    const int base = blk * CHUNK;
#pragma unroll
    for (int i = 0; i < CHUNK / 1024; ++i) {
        const int j = i * 1024 + tid * 4;
        const float* p = smem + HALO + j;
        float4 o = quad_fir(p, c);
        o.x *= inv; o.y *= inv; o.z *= inv; o.w *= inv;
        *(float4*)(out + base + j) = o;
    }
}

extern "C" void kernel_launch(void* const* d_in, const int* in_sizes, int n_in,
                              void* d_out, int out_size, void* d_ws, size_t ws_size,
                              hipStream_t stream) {
    const float* x = (const float*)d_in[0];       // input_sig [1, T]
    const float* g = (const float*)d_in[1];       // feedback_gain [8]
    const float* Q = (const float*)d_in[2];       // orthogonal_matrix [8,8]
    float* out = (float*)d_out;
    float* slots = (float*)d_ws;                  // 2048 per-block maxes
                                                  // (written unconditionally by
                                                  //  pass A before pass B reads)

    fdn_max  <<<dim3(NBLK), dim3(256), 0, stream>>>(x, g, Q, slots);
    fdn_write<<<dim3(NBLK), dim3(256), 0, stream>>>(x, g, Q, slots, out);
}

// Round 7
// 106.342 us; speedup vs baseline: 1.9250x; 1.0530x over previous
//
#include <hip/hip_runtime.h>

// FDN reverb == 8-tap sparse FIR + 50/50 mix + global max-abs normalize.
// Plain stream-ordered two-pass (cooperative grid.sync measured ~100us of
// overhead in R3/R4 — do not use):
//   pass A: LDS-staged FIR, block max only -> slots[blk]  (no 32MB store)
//   pass B: reduce slots -> 1/max, recompute FIR, scale, single 32MB write
// LDS reads exploit delay parity: D1,D2,D6 = 0 mod 4 -> ds_read_b128,
// D4 = 2 mod 4 -> 2x ds_read_b64, D0,D3,D5,D7 = 1 mod 4 -> b32+b64+b32.
// Block swizzle: consecutive blocks round-robin XCDs, so give each XCD a
// contiguous 4MB region of x (== its L2 size) for halo/stage L2 locality.
#define T_LEN 8388608
#define CHUNK 4096               // outputs per block
#define HALO  3840               // >= max delay (3825), multiple of 4
#define LDSF  (HALO + CHUNK)     // 7936 floats = 31744 B -> 5 blocks/CU
#define NBLK  (T_LEN / CHUNK)    // 2048 blocks

#define D0 1425   // %4 == 1
#define D1 1780   // %4 == 0
#define D2 1972   // %4 == 0
#define D3 2097   // %4 == 1
#define D4 2558   // %4 == 2
#define D5 2961   // %4 == 1
#define D6 3508   // %4 == 0
#define D7 3825   // %4 == 1

typedef float floatx4 __attribute__((ext_vector_type(4)));  // native vec for
                                                            // nontemporal store

__device__ __forceinline__ int swz(int b) {
    // phys block -> logical chunk: XCD k (b%8) owns contiguous [k*256,(k+1)*256)
    return (b & 7) * (NBLK / 8) + (b >> 3);
}

__device__ __forceinline__ void load_odd(const float* q, float* v) {
    // q is (3 mod 4)-dword aligned: scalar, aligned float2, scalar
    float  a  = q[0];
    float2 b  = *(const float2*)(q + 1);
    float  c  = q[3];
    v[0] = a; v[1] = b.x; v[2] = b.y; v[3] = c;
}

// Compute 4 outputs at LDS pointer p (16B-aligned), coefficients c[8].
__device__ __forceinline__ float4 quad_fir(const float* __restrict__ p,
                                           const float* __restrict__ c) {
    float4 dry = *(const float4*)(p);
    float4 t1  = *(const float4*)(p - D1);   // b128
    float4 t2  = *(const float4*)(p - D2);   // b128
    float4 t6  = *(const float4*)(p - D6);   // b128
    float2 t4a = *(const float2*)(p - D4);   // b64 (p-D4 is 2 mod 4)
    float2 t4b = *(const float2*)(p - D4 + 2);
    float t0v[4], t3v[4], t5v[4], t7v[4];
    load_odd(p - D0, t0v);
    load_odd(p - D3, t3v);
    load_odd(p - D5, t5v);
    load_odd(p - D7, t7v);
    float t4v[4] = {t4a.x, t4a.y, t4b.x, t4b.y};

    float4 o;
#pragma unroll
    for (int k = 0; k < 4; ++k) {
        float wet = 0.f;
        wet = fmaf(c[0], t0v[k],      wet);
        wet = fmaf(c[1], (&t1.x)[k],  wet);
        wet = fmaf(c[2], (&t2.x)[k],  wet);
        wet = fmaf(c[3], t3v[k],      wet);
        wet = fmaf(c[4], t4v[k],      wet);
        wet = fmaf(c[5], t5v[k],      wet);
        wet = fmaf(c[6], (&t6.x)[k],  wet);
        wet = fmaf(c[7], t7v[k],      wet);
        (&o.x)[k] = fmaf(0.5f, wet, 0.5f * (&dry.x)[k]);
    }
    return o;
}

// Stage [blk*CHUNK - HALO, blk*CHUNK + CHUNK) into LDS; zeros before t=0.
__device__ __forceinline__ void stage(const float* __restrict__ x, float* smem,
                                      int blk, int tid) {
    const long gs = (long)blk * CHUNK - HALO;
    for (int v4 = tid; v4 < LDSF / 4; v4 += 256) {
        long ga = gs + (long)v4 * 4;
        float4 val = make_float4(0.f, 0.f, 0.f, 0.f);
        if (ga >= 0) val = *(const float4*)(x + ga);
        *(float4*)(smem + v4 * 4) = val;
    }
}

__device__ __forceinline__ void load_coeffs(const float* __restrict__ g,
                                            const float* __restrict__ Q,
                                            float* csh, int tid) {
    if (tid < 8) {
        float s = 0.f;
#pragma unroll
        for (int j = 0; j < 8; ++j) s += Q[j * 8 + tid];
        csh[tid] = s * g[tid];
    }
}

// Pass A: FIR + block max -> slots[blk]. No output store.
__global__ __launch_bounds__(256) void fdn_max(
    const float* __restrict__ x, const float* __restrict__ g,
    const float* __restrict__ Q, float* __restrict__ slots) {
    __shared__ __align__(16) float smem[LDSF];
    __shared__ float csh[8];
    __shared__ float wmax[4];

    const int tid = threadIdx.x;
    const int blk = swz(blockIdx.x);

    load_coeffs(g, Q, csh, tid);
    stage(x, smem, blk, tid);
    __syncthreads();

    float c[8];
#pragma unroll
    for (int n = 0; n < 8; ++n) c[n] = csh[n];

    float m = 0.f;
#pragma unroll
    for (int i = 0; i < CHUNK / 1024; ++i) {
        const float* p = smem + HALO + i * 1024 + tid * 4;
        float4 o = quad_fir(p, c);
        m = fmaxf(m, fmaxf(fmaxf(fabsf(o.x), fabsf(o.y)),
                           fmaxf(fabsf(o.z), fabsf(o.w))));
    }

#pragma unroll
    for (int off = 32; off > 0; off >>= 1) m = fmaxf(m, __shfl_down(m, off, 64));
    if ((tid & 63) == 0) wmax[tid >> 6] = m;
    __syncthreads();
    if (tid == 0)
        slots[blk] = fmaxf(fmaxf(wmax[0], wmax[1]), fmaxf(wmax[2], wmax[3]));
}

// Pass B: reduce slots -> inv, recompute FIR, scale, write (nontemporal).
__global__ __launch_bounds__(256) void fdn_write(
    const float* __restrict__ x, const float* __restrict__ g,
    const float* __restrict__ Q, const float* __restrict__ slots,
    float* __restrict__ out) {
    __shared__ __align__(16) float smem[LDSF];
    __shared__ float csh[8];
    __shared__ float wmax[4];

    const int tid = threadIdx.x;
    const int blk = swz(blockIdx.x);

    load_coeffs(g, Q, csh, tid);

    // each thread covers 8 of the 2048 slots (two float4 loads)
    float4 s0 = *(const float4*)(slots + tid * 8);
    float4 s1 = *(const float4*)(slots + tid * 8 + 4);

    stage(x, smem, blk, tid);

    float m = fmaxf(fmaxf(fmaxf(s0.x, s0.y), fmaxf(s0.z, s0.w)),
                    fmaxf(fmaxf(s1.x, s1.y), fmaxf(s1.z, s1.w)));
#pragma unroll
    for (int off = 32; off > 0; off >>= 1) m = fmaxf(m, __shfl_down(m, off, 64));
    if ((tid & 63) == 0) wmax[tid >> 6] = m;
    __syncthreads();   // covers staging + wmax

    const float inv = 1.0f / fmaxf(fmaxf(wmax[0], wmax[1]),
                                   fmaxf(wmax[2], wmax[3]));
    float c[8];
#pragma unroll
    for (int n = 0; n < 8; ++n) c[n] = csh[n];

    const int base = blk * CHUNK;
#pragma unroll
    for (int i = 0; i < CHUNK / 1024; ++i) {
        const int j = i * 1024 + tid * 4;
        const float* p = smem + HALO + j;
        float4 o = quad_fir(p, c);
        floatx4 ov;
        ov.x = o.x * inv; ov.y = o.y * inv;
        ov.z = o.z * inv; ov.w = o.w * inv;
        __builtin_nontemporal_store(ov, (floatx4*)(out + base + j));
    }
}

extern "C" void kernel_launch(void* const* d_in, const int* in_sizes, int n_in,
                              void* d_out, int out_size, void* d_ws, size_t ws_size,
                              hipStream_t stream) {
    const float* x = (const float*)d_in[0];       // input_sig [1, T]
    const float* g = (const float*)d_in[1];       // feedback_gain [8]
    const float* Q = (const float*)d_in[2];       // orthogonal_matrix [8,8]
    float* out = (float*)d_out;
    float* slots = (float*)d_ws;                  // 2048 per-block maxes
                                                  // (written unconditionally by
                                                  //  pass A before pass B reads)

    fdn_max  <<<dim3(NBLK), dim3(256), 0, stream>>>(x, g, Q, slots);
    fdn_write<<<dim3(NBLK), dim3(256), 0, stream>>>(x, g, Q, slots, out);
}